// Round 17
// baseline (128.354 us; speedup 1.0000x reference)
//
#include <hip/hip_runtime.h>
#include <hip/hip_fp16.h>

#define D 300
#define NS 256
#define NA 256
#define W 8
#define NCHUNK 10     // K padded to 10 chunks of 32 (320)

typedef _Float16 half8 __attribute__((ext_vector_type(8)));
typedef float f32x4 __attribute__((ext_vector_type(4)));

// ---- fused single launch: blocks 0..255 = GEMM tiles (gather-on-the-fly);
//      blocks 256..319 = out2 (one wave per sen category) ----
__global__ __launch_bounds__(256, 1) void k_all(const float* __restrict__ emb,
                                                const int* __restrict__ sen_cats,
                                                const int* __restrict__ ann_cats,
                                                const int* __restrict__ none_idx,
                                                float* __restrict__ out) {
    int blk = blockIdx.x;
    int tid = threadIdx.x;

    if (blk >= 256) {
        // ----- out2: one wave per sen category (w-ascending fp32 adds) -----
        int wv = tid >> 6, lane = tid & 63;
        int cb = (blk - 256) * 4 + wv;
        float4 s0 = make_float4(0.f, 0.f, 0.f, 0.f);
        float4 s1 = make_float4(0.f, 0.f, 0.f, 0.f);
#pragma unroll
        for (int w = 0; w < W; ++w) {
            int cat = sen_cats[cb * W + w];
            const float4* src = reinterpret_cast<const float4*>(emb + (size_t)cat * D);
            float4 v0 = src[lane];
            s0.x += v0.x; s0.y += v0.y; s0.z += v0.z; s0.w += v0.w;
            if (lane < 11) {
                float4 v1 = src[lane + 64];
                s1.x += v1.x; s1.y += v1.y; s1.z += v1.z; s1.w += v1.w;
            }
        }
        float4* o = reinterpret_cast<float4*>(out + NS * NA + (size_t)cb * D);
        o[lane] = s0;
        if (lane < 11) o[lane + 64] = s1;
        return;
    }

    // ----- GEMM tile block -----
    __shared__ float cosld[128][128];   // 64 KB exactly

    int wv = tid >> 6, lane = tid & 63;
    int wy = wv >> 1, wx = wv & 1;      // wave's 64x64 quadrant
    int lr = lane & 15;
    int lk = lane >> 4;
    int by = blk >> 4, bx = blk & 15;
    int nidx = none_idx[0];

    // rows this lane gathers: A row = by*128 + wy*64 + m*16 + lr (k-slice lk*8..)
    const float* pA[4];
    const float* pB[4];
    int catA[4];
#pragma unroll
    for (int m = 0; m < 4; ++m) {
        catA[m] = sen_cats[by * 128 + wy * 64 + m * 16 + lr];
        pA[m] = emb + (size_t)catA[m] * D;
    }
#pragma unroll
    for (int n = 0; n < 4; ++n) {
        int cB = ann_cats[bx * 128 + wx * 64 + n * 16 + lr];
        pB[n] = emb + (size_t)cB * D;
    }

    f32x4 acc[4][4] = {};
    float na[4] = {0.f, 0.f, 0.f, 0.f};
    float nb[4] = {0.f, 0.f, 0.f, 0.f};

#pragma unroll
    for (int c = 0; c < NCHUNK; ++c) {
        int k0 = c * 32 + lk * 8;
        // masks for the K-pad (k >= 300) in chunk 9
        bool f0 = (c < 9) || (lk <= 1);   // k0..k0+3   (c==9: lk0:288, lk1:296 valid)
        bool f1 = (c < 9) || (lk == 0);   // k0+4..k0+7 (c==9: lk1 would be 300..303)
        half8 Ah[4], Bh[4];
#pragma unroll
        for (int m = 0; m < 4; ++m) {
            float4 v0 = make_float4(0.f, 0.f, 0.f, 0.f);
            float4 v1 = make_float4(0.f, 0.f, 0.f, 0.f);
            if (f0) v0 = *reinterpret_cast<const float4*>(pA[m] + k0);
            if (f1) v1 = *reinterpret_cast<const float4*>(pA[m] + k0 + 4);
            na[m] = fmaf(v0.x, v0.x, na[m]); na[m] = fmaf(v0.y, v0.y, na[m]);
            na[m] = fmaf(v0.z, v0.z, na[m]); na[m] = fmaf(v0.w, v0.w, na[m]);
            na[m] = fmaf(v1.x, v1.x, na[m]); na[m] = fmaf(v1.y, v1.y, na[m]);
            na[m] = fmaf(v1.z, v1.z, na[m]); na[m] = fmaf(v1.w, v1.w, na[m]);
            Ah[m][0] = (_Float16)v0.x; Ah[m][1] = (_Float16)v0.y;
            Ah[m][2] = (_Float16)v0.z; Ah[m][3] = (_Float16)v0.w;
            Ah[m][4] = (_Float16)v1.x; Ah[m][5] = (_Float16)v1.y;
            Ah[m][6] = (_Float16)v1.z; Ah[m][7] = (_Float16)v1.w;
        }
#pragma unroll
        for (int n = 0; n < 4; ++n) {
            float4 v0 = make_float4(0.f, 0.f, 0.f, 0.f);
            float4 v1 = make_float4(0.f, 0.f, 0.f, 0.f);
            if (f0) v0 = *reinterpret_cast<const float4*>(pB[n] + k0);
            if (f1) v1 = *reinterpret_cast<const float4*>(pB[n] + k0 + 4);
            nb[n] = fmaf(v0.x, v0.x, nb[n]); nb[n] = fmaf(v0.y, v0.y, nb[n]);
            nb[n] = fmaf(v0.z, v0.z, nb[n]); nb[n] = fmaf(v0.w, v0.w, nb[n]);
            nb[n] = fmaf(v1.x, v1.x, nb[n]); nb[n] = fmaf(v1.y, v1.y, nb[n]);
            nb[n] = fmaf(v1.z, v1.z, nb[n]); nb[n] = fmaf(v1.w, v1.w, nb[n]);
            Bh[n][0] = (_Float16)v0.x; Bh[n][1] = (_Float16)v0.y;
            Bh[n][2] = (_Float16)v0.z; Bh[n][3] = (_Float16)v0.w;
            Bh[n][4] = (_Float16)v1.x; Bh[n][5] = (_Float16)v1.y;
            Bh[n][6] = (_Float16)v1.z; Bh[n][7] = (_Float16)v1.w;
        }
#pragma unroll
        for (int m = 0; m < 4; ++m)
#pragma unroll
            for (int n = 0; n < 4; ++n)
                acc[m][n] = __builtin_amdgcn_mfma_f32_16x16x32_f16(Ah[m], Bh[n], acc[m][n], 0, 0, 0);
    }

    // norms: reduce the 4 lk-slices of each row; all lanes get the row sum
    float scaleA[4], scaleB[4];
#pragma unroll
    for (int m = 0; m < 4; ++m) {
        float s = na[m];
        s += __shfl_xor(s, 16, 64);
        s += __shfl_xor(s, 32, 64);
        scaleA[m] = (catA[m] == nidx) ? 0.f : (float)(1.0 / sqrt((double)s));
    }
#pragma unroll
    for (int n = 0; n < 4; ++n) {
        float s = nb[n];
        s += __shfl_xor(s, 16, 64);
        s += __shfl_xor(s, 32, 64);
        scaleB[n] = (float)(1.0 / sqrt((double)s));
    }

    // epilogue: cosine scale (C/D: col=lane&15, row=(lane>>4)*4+reg) -> LDS
    // rowScale for row m*16 + lk*4 + r lives in lane lr' = lk*4+r -> shuffle
#pragma unroll
    for (int m = 0; m < 4; ++m) {
        int rbase = wy * 64 + m * 16 + lk * 4;
#pragma unroll
        for (int r = 0; r < 4; ++r) {
            float rf = __shfl(scaleA[m], lk * 4 + r, 64);
#pragma unroll
            for (int n = 0; n < 4; ++n) {
                int lc = wx * 64 + n * 16 + lr;
                cosld[rbase + r][lc] = acc[m][n][r] * rf * scaleB[n];
            }
        }
    }
    __syncthreads();

    // order-dependent fold: one (s,a) pair per thread, w-major order
    int pi = tid >> 4, pj = tid & 15;
    float cur = 0.f;
#pragma unroll
    for (int w = 0; w < W; ++w) {
        const float* rowp = &cosld[pi * 8 + w][pj * 8];
#pragma unroll
        for (int v = 0; v < W; ++v) {
            float sv = rowp[v];
            cur = (sv >= cur || sv < 0.f) ? sv : cur;
        }
    }
    out[(by * 16 + pi) * NA + (bx * 16 + pj)] = cur;
}

extern "C" void kernel_launch(void* const* d_in, const int* in_sizes, int n_in,
                              void* d_out, int out_size, void* d_ws, size_t ws_size,
                              hipStream_t stream) {
    const float* emb = (const float*)d_in[0];
    const int* sen = (const int*)d_in[1];
    const int* ann = (const int*)d_in[2];
    const int* none = (const int*)d_in[3];
    float* out = (float*)d_out;

    hipLaunchKernelGGL(k_all, dim3(320), dim3(256), 0, stream,
                       emb, sen, ann, none, out);
}

// Round 18
// 23.543 us; speedup vs baseline: 5.4520x; 5.4520x over previous
//
#include <hip/hip_runtime.h>
#include <hip/hip_fp16.h>

#define D 300
#define NS 256
#define NA 256
#define W 8
#define NPH 5        // 5 K-phases x 64 elements (K padded 300 -> 320)

typedef _Float16 half8 __attribute__((ext_vector_type(8)));
typedef float f32x4 __attribute__((ext_vector_type(4)));

// Single dispatch: 256 blocks (one 128x128 tile each, 1/CU).
// LDS (64 KB): stage[2 bufs][A 16KB + B 16KB]; after MFMA, buf0 -> fp16 cos
// tile [128][128], buf1 -> rsc[256] scales.
__global__ __launch_bounds__(256, 1) void k_all(const float* __restrict__ emb,
                                                const int* __restrict__ sen_cats,
                                                const int* __restrict__ ann_cats,
                                                const int* __restrict__ none_idx,
                                                float* __restrict__ out) {
    __shared__ float smem[16384];   // 64 KB
    _Float16* stage = reinterpret_cast<_Float16*>(smem);  // half-indexed
    float* rsc = smem + 8192;                             // overlays buf1
    _Float16* cosld = reinterpret_cast<_Float16*>(smem);  // overlays buf0

    int tid = threadIdx.x;
    int blk = blockIdx.x;
    int by = blk >> 4, bx = blk & 15;
    int wv = tid >> 6, lane = tid & 63;
    int wy = wv >> 1, wx = wv & 1;
    int lr = lane & 15, lk = lane >> 4;

    // ---- staging map: group g (16 lanes, f0) covers rows g+j*16, j=0..15 ----
    int g = tid >> 4, f0 = tid & 15;
    int c0 = f0 >> 3, lk0 = (f0 & 7) >> 1, e0 = (f0 & 1) * 4;  // from klocal=f0*4
    const float* rowp[16];
    int catA[8];
#pragma unroll
    for (int j = 0; j < 8; ++j) {              // A rows (sen)
        catA[j] = sen_cats[by * 128 + g + j * 16];
        rowp[j] = emb + (size_t)catA[j] * D;
    }
#pragma unroll
    for (int j = 8; j < 16; ++j) {             // B rows (ann)
        int cb = ann_cats[bx * 128 + g + (j - 8) * 16];
        rowp[j] = emb + (size_t)cb * D;
    }
    // half-index of this thread's ds_write slot for row j in buffer b:
    //   A: b*16384 + ((j*2+c0)*64 + lk0*16 + g)*8 + e0
    //   B: b*16384 + 8192 + (((j-8)*2+c0)*64 + lk0*16 + g)*8 + e0

    float4 pf[16];
    float na[16];
#pragma unroll
    for (int j = 0; j < 16; ++j) na[j] = 0.f;

#define PH_LOAD(p)                                                            \
    {                                                                         \
        int gk = (p) * 64 + f0 * 4;                                           \
        bool ok = ((p) < 4) || (f0 <= 10);   /* k<=296 valid (K=300) */       \
        _Pragma("unroll")                                                     \
        for (int j = 0; j < 16; ++j)                                          \
            pf[j] = ok ? *reinterpret_cast<const float4*>(rowp[j] + gk)       \
                       : make_float4(0.f, 0.f, 0.f, 0.f);                     \
    }
#define PH_WRITE(b)                                                           \
    {                                                                         \
        _Pragma("unroll")                                                     \
        for (int j = 0; j < 16; ++j) {                                        \
            float4 v = pf[j];                                                 \
            na[j] = fmaf(v.x, v.x, na[j]); na[j] = fmaf(v.y, v.y, na[j]);     \
            na[j] = fmaf(v.z, v.z, na[j]); na[j] = fmaf(v.w, v.w, na[j]);     \
            ushort4 h;                                                        \
            h.x = __half_as_ushort(__float2half(v.x));                        \
            h.y = __half_as_ushort(__float2half(v.y));                        \
            h.z = __half_as_ushort(__float2half(v.z));                        \
            h.w = __half_as_ushort(__float2half(v.w));                        \
            int rt = (j < 8) ? j : (j - 8);                                   \
            int off = (b) * 16384 + ((j < 8) ? 0 : 8192) +                    \
                      ((rt * 2 + c0) * 64 + lk0 * 16 + g) * 8 + e0;           \
            *reinterpret_cast<ushort4*>(stage + off) = h;                     \
        }                                                                     \
    }

    f32x4 acc[4][4] = {};

    // prologue
    PH_LOAD(0);
    PH_WRITE(0);
    PH_LOAD(1);
    __syncthreads();

#pragma unroll
    for (int p = 0; p < NPH; ++p) {
        if (p + 1 < NPH) {
            PH_WRITE((p + 1) & 1);
            if (p + 2 < NPH) PH_LOAD(p + 2);
        }
        int bb = (p & 1) * 16384;
#pragma unroll
        for (int c = 0; c < 2; ++c) {          // global chunk 2p+c (ascending)
            half8 Ah[4], Bh[4];
#pragma unroll
            for (int m = 0; m < 4; ++m)
                Ah[m] = *reinterpret_cast<const half8*>(
                    stage + bb + (((wy * 4 + m) * 2 + c) * 64 + lane) * 8);
#pragma unroll
            for (int n = 0; n < 4; ++n)
                Bh[n] = *reinterpret_cast<const half8*>(
                    stage + bb + 8192 + (((wx * 4 + n) * 2 + c) * 64 + lane) * 8);
#pragma unroll
            for (int m = 0; m < 4; ++m)
#pragma unroll
                for (int n = 0; n < 4; ++n)
                    acc[m][n] = __builtin_amdgcn_mfma_f32_16x16x32_f16(
                        Ah[m], Bh[n], acc[m][n], 0, 0, 0);
        }
        __syncthreads();
    }

    // ---- scales into rsc (overlays buf1; all stage reads are done) ----
    int nidx = none_idx[0];
#pragma unroll
    for (int j = 0; j < 16; ++j) {
        float s = na[j];
        s += __shfl_xor(s, 1, 64);
        s += __shfl_xor(s, 2, 64);
        s += __shfl_xor(s, 4, 64);
        s += __shfl_xor(s, 8, 64);             // row sum across the 16-lane group
        if (f0 == 0) {
            float rn = (float)(1.0 / sqrt((double)s));
            if (j < 8 && catA[j] == nidx) rn = 0.f;
            rsc[g + ((j < 8) ? j * 16 : 128 + (j - 8) * 16)] = rn;
        }
    }
    __syncthreads();

    // ---- epilogue: cos -> fp16 tile in buf0 (C/D: col=lane&15, row=lk*4+reg) ----
#pragma unroll
    for (int m = 0; m < 4; ++m) {
        int rbase = wy * 64 + m * 16 + lk * 4;
#pragma unroll
        for (int r = 0; r < 4; ++r) {
            float sA = rsc[rbase + r];
#pragma unroll
            for (int n = 0; n < 4; ++n) {
                int lc = wx * 64 + n * 16 + lr;
                float sB = rsc[128 + lc];
                cosld[(rbase + r) * 128 + lc] = (_Float16)(acc[m][n][r] * sA * sB);
            }
        }
    }
    __syncthreads();

    // ---- order-dependent fold: one (s,a) pair per thread, w-major ----
    int pi = tid >> 4, pj = tid & 15;
    float cur = 0.f;
#pragma unroll
    for (int w = 0; w < W; ++w) {
        const _Float16* rp = &cosld[(pi * 8 + w) * 128 + pj * 8];
#pragma unroll
        for (int v = 0; v < W; ++v) {
            float sv = (float)rp[v];
            cur = (sv >= cur || sv < 0.f) ? sv : cur;
        }
    }
    out[(by * 16 + pi) * NA + (bx * 16 + pj)] = cur;

    // ---- out2 tail: wave 0 of block b computes sen category b ----
    if (wv == 0) {
        int cb = blk;
        float4 s0 = make_float4(0.f, 0.f, 0.f, 0.f);
        float4 s1 = make_float4(0.f, 0.f, 0.f, 0.f);
#pragma unroll
        for (int w = 0; w < W; ++w) {          // w-ascending fp32 adds (ref order)
            int cat = sen_cats[cb * W + w];
            const float4* src = reinterpret_cast<const float4*>(emb + (size_t)cat * D);
            float4 v0 = src[lane];
            s0.x += v0.x; s0.y += v0.y; s0.z += v0.z; s0.w += v0.w;
            if (lane < 11) {
                float4 v1 = src[lane + 64];
                s1.x += v1.x; s1.y += v1.y; s1.z += v1.z; s1.w += v1.w;
            }
        }
        float4* o = reinterpret_cast<float4*>(out + NS * NA + (size_t)cb * D);
        o[lane] = s0;
        if (lane < 11) o[lane + 64] = s1;
    }
#undef PH_LOAD
#undef PH_WRITE
}

extern "C" void kernel_launch(void* const* d_in, const int* in_sizes, int n_in,
                              void* d_out, int out_size, void* d_ws, size_t ws_size,
                              hipStream_t stream) {
    const float* emb = (const float*)d_in[0];
    const int* sen = (const int*)d_in[1];
    const int* ann = (const int*)d_in[2];
    const int* none = (const int*)d_in[3];
    float* out = (float*)d_out;

    hipLaunchKernelGGL(k_all, dim3(256), dim3(256), 0, stream,
                       emb, sen, ann, none, out);
}